// Round 12
// baseline (929.318 us; speedup 1.0000x reference)
//
#include <hip/hip_runtime.h>

#define IN_C 256
#define HID_C 256
#define OUT_C 128
#define NUM_GRAPHS 64
#define NBLK 256    // blocks for hist/scatter phases
#define NBUCK 1024  // dst buckets (bucket = dst >> 7), N <= 131072

typedef _Float16 half4v __attribute__((ext_vector_type(4)));
typedef _Float16 half8v __attribute__((ext_vector_type(8)));
typedef float f32x4 __attribute__((ext_vector_type(4)));
typedef float f32x8 __attribute__((ext_vector_type(8)));

// ---------------- CSR build: atomic-free (LDS-only atomics) ----------------

__global__ __launch_bounds__(256) void hist_kernel(const int* __restrict__ dst, int E,
                                                   int* __restrict__ ghist) {
    __shared__ int h[NBUCK];
    int tid = threadIdx.x;
#pragma unroll
    for (int j = 0; j < NBUCK / 256; ++j) h[tid + j * 256] = 0;
    __syncthreads();
    int ch = (E + NBLK - 1) / NBLK;
    int base = blockIdx.x * ch;
    int end = min(base + ch, E);
    for (int i = base + tid; i < end; i += 256)
        atomicAdd(&h[dst[i] >> 7], 1);
    __syncthreads();
#pragma unroll
    for (int j = 0; j < NBUCK / 256; ++j) {
        int b = tid + j * 256;
        ghist[b * NBLK + blockIdx.x] = h[b];
    }
}

__global__ __launch_bounds__(256) void scan_bsum_kernel(const int* __restrict__ cnt, int M,
                                                        int* __restrict__ bsum) {
    __shared__ int s[256];
    int tid = threadIdx.x;
    int i = blockIdx.x * 256 + tid;
    int v = (i < M) ? cnt[i] : 0;
    s[tid] = v;
    __syncthreads();
    for (int off = 128; off > 0; off >>= 1) {
        if (tid < off) s[tid] += s[tid + off];
        __syncthreads();
    }
    if (tid == 0) bsum[blockIdx.x] = s[0];
}

__global__ __launch_bounds__(1024) void scan_boff_kernel(const int* __restrict__ bsum, int nb,
                                                         int* __restrict__ boff) {
    __shared__ int s[1024];
    int tid = threadIdx.x;
    int v = (tid < nb) ? bsum[tid] : 0;
    s[tid] = v;
    __syncthreads();
    for (int off = 1; off < 1024; off <<= 1) {
        int t = (tid >= off) ? s[tid - off] : 0;
        __syncthreads();
        s[tid] += t;
        __syncthreads();
    }
    if (tid < nb) boff[tid] = s[tid] - v;  // exclusive
}

__global__ __launch_bounds__(256) void scan_write_kernel(const int* __restrict__ cnt, int M,
                                                         const int* __restrict__ boff,
                                                         int* __restrict__ S) {
    __shared__ int s[256];
    int tid = threadIdx.x;
    int i = blockIdx.x * 256 + tid;
    int v = (i < M) ? cnt[i] : 0;
    s[tid] = v;
    __syncthreads();
    for (int off = 1; off < 256; off <<= 1) {
        int t = (tid >= off) ? s[tid - off] : 0;
        __syncthreads();
        s[tid] += t;
        __syncthreads();
    }
    int incl = s[tid];
    int bo = boff[blockIdx.x];
    if (i < M) S[i] = bo + incl - v;
    if (i == M - 1) S[M] = bo + incl;
}

// Phase 2: scatter edges, packed 4B: (dst&127)<<17 | src   (src < 2^17)

__global__ __launch_bounds__(256) void bucket_scatter_kernel(const int* __restrict__ src,
                                                             const int* __restrict__ dst, int E,
                                                             const int* __restrict__ S,
                                                             unsigned int* __restrict__ sorted) {
    __shared__ int cur[NBUCK];
    int tid = threadIdx.x;
#pragma unroll
    for (int j = 0; j < NBUCK / 256; ++j) {
        int b = tid + j * 256;
        cur[b] = S[b * NBLK + blockIdx.x];
    }
    __syncthreads();
    int ch = (E + NBLK - 1) / NBLK;
    int base = blockIdx.x * ch;
    int end = min(base + ch, E);
    for (int i = base + tid; i < end; i += 256) {
        int d = dst[i], s = src[i];
        int p = atomicAdd(&cur[d >> 7], 1);  // LDS atomic -> global position
        sorted[p] = ((unsigned int)(d & 127) << 17) | (unsigned int)s;
    }
}

// Phase 3: per-bucket (128 nodes) local count/scan/scatter -> rowptr, csr

__global__ __launch_bounds__(256) void bucket_csr_kernel(const unsigned int* __restrict__ sorted,
                                                         const int* __restrict__ S,
                                                         int* __restrict__ rowptr,
                                                         int* __restrict__ csr, int N) {
    __shared__ int cnt[128], sa[128], sb[128], cur[128];
    int b = blockIdx.x;
    int tid = threadIdx.x;
    int lo = S[b << 8];            // b*NBLK
    int hi = S[(b + 1) << 8];
    if (tid < 128) cnt[tid] = 0;
    __syncthreads();
    for (int i = lo + tid; i < hi; i += 256)
        atomicAdd(&cnt[sorted[i] >> 17], 1);
    __syncthreads();
    if (tid < 128) sa[tid] = cnt[tid];
    __syncthreads();
#pragma unroll
    for (int st = 1; st < 128; st <<= 1) {
        if (tid < 128) sb[tid] = sa[tid] + ((tid >= st) ? sa[tid - st] : 0);
        __syncthreads();
        if (tid < 128) sa[tid] = sb[tid];
        __syncthreads();
    }
    if (tid < 128) {
        int offx = sa[tid] - cnt[tid];
        int idx = (b << 7) + tid;
        if (idx <= N) rowptr[idx] = lo + offx;
        cur[tid] = offx;
    }
    __syncthreads();
    for (int i = lo + tid; i < hi; i += 256) {
        unsigned int e = sorted[i];
        int p = atomicAdd(&cur[e >> 17], 1);
        csr[lo + p] = (int)(e & 0x1FFFFu);
    }
}

__global__ __launch_bounds__(256) void dinv_kernel(const int* __restrict__ rowptr,
                                                   float* __restrict__ dinv, int N) {
    int i = blockIdx.x * 256 + threadIdx.x;
    if (i < N) {
        int deg = rowptr[i + 1] - rowptr[i];
        dinv[i] = rsqrtf((float)(deg + 1));  // +1 self loop
    }
}

// ---------------- dtype prep: all three W [K][C] f32 -> Wt [C][K] f16 ----------------

__global__ __launch_bounds__(256) void wt_all_kernel(const float* __restrict__ W1,
                                                     const float* __restrict__ W2,
                                                     const float* __restrict__ W3,
                                                     _Float16* __restrict__ wt1,
                                                     _Float16* __restrict__ wt2,
                                                     _Float16* __restrict__ wt3) {
    int idx = blockIdx.x * 256 + threadIdx.x;
    const int S1 = IN_C * HID_C;           // 65536
    const int S2 = S1 + HID_C * HID_C;     // 131072
    const int S3 = S2 + HID_C * OUT_C;     // 163840
    if (idx < S1) {
        int k = idx >> 8, c = idx & 255;   // C=256
        wt1[c * IN_C + k] = (_Float16)W1[idx];
    } else if (idx < S2) {
        int li = idx - S1;
        int k = li >> 8, c = li & 255;     // C=256
        wt2[c * HID_C + k] = (_Float16)W2[idx - S1];
    } else if (idx < S3) {
        int li = idx - S2;
        int k = li >> 7, c = li & 127;     // C=128
        wt3[c * HID_C + k] = (_Float16)W3[li];
    }
}

// ---------------- MFMA f16 GEMM, BM=128 x BN=256, 512 threads (8 waves) ----------------

template <typename InT>
__global__ __launch_bounds__(512) void gemm_f16_wide(const InT* __restrict__ A,
                                                     const _Float16* __restrict__ Bt,
                                                     const float* __restrict__ dinv,
                                                     _Float16* __restrict__ HS,
                                                     int nRows) {
    constexpr int K = 256;
    constexpr int BK = 32;
    constexpr int LDR = 40;
    constexpr int BN = 256;

    __shared__ __align__(16) _Float16 Al[128 * LDR];
    __shared__ __align__(16) _Float16 Bl[256 * LDR];

    const int tid = threadIdx.x;
    const int wave = tid >> 6;       // 0..7
    const int lane = tid & 63;
    const int row0 = blockIdx.x << 7;  // BM=128

    const int ar = tid >> 2;          // 0..127
    const int ac = (tid & 3) << 3;    // {0,8,16,24}
    const int arow = min(row0 + ar, nRows - 1);

    const int rh = wave >> 2;         // row half 0..1
    const int cq = wave & 3;          // col quad 0..3
    const int fr = lane & 15;
    const int k8 = lane >> 4;

    f32x4 acc[4][4] = {};

    for (int k0 = 0; k0 < K; k0 += BK) {
        half8v av;
        if constexpr (sizeof(InT) == 2) {
            av = *(const half8v*)((const _Float16*)A + (size_t)arow * K + k0 + ac);
        } else {
            const float* ap = (const float*)A + (size_t)arow * K + k0 + ac;
            f32x4 lo = *(const f32x4*)(ap);
            f32x4 hi = *(const f32x4*)(ap + 4);
            half4v l = __builtin_convertvector(lo, half4v);
            half4v h = __builtin_convertvector(hi, half4v);
            av = __builtin_shufflevector(l, h, 0, 1, 2, 3, 4, 5, 6, 7);
        }
        half8v bv0 = *(const half8v*)(Bt + (size_t)ar * K + k0 + ac);
        half8v bv1 = *(const half8v*)(Bt + (size_t)(ar + 128) * K + k0 + ac);
        __syncthreads();
        *(half8v*)(Al + ar * LDR + ac) = av;
        *(half8v*)(Bl + ar * LDR + ac) = bv0;
        *(half8v*)(Bl + (ar + 128) * LDR + ac) = bv1;
        __syncthreads();

        half8v af[4], bf[4];
#pragma unroll
        for (int m = 0; m < 4; ++m)
            af[m] = *(const half8v*)(Al + (rh * 64 + m * 16 + fr) * LDR + k8 * 8);
#pragma unroll
        for (int n = 0; n < 4; ++n)
            bf[n] = *(const half8v*)(Bl + (cq * 64 + n * 16 + fr) * LDR + k8 * 8);
#pragma unroll
        for (int m = 0; m < 4; ++m)
#pragma unroll
            for (int n = 0; n < 4; ++n)
                acc[m][n] = __builtin_amdgcn_mfma_f32_16x16x32_f16(af[m], bf[n], acc[m][n], 0, 0, 0);
    }

#pragma unroll
    for (int m = 0; m < 4; ++m) {
        int rb = row0 + rh * 64 + m * 16 + k8 * 4;
        float s[4];
#pragma unroll
        for (int r = 0; r < 4; ++r) s[r] = (rb + r < nRows) ? dinv[rb + r] : 0.f;
#pragma unroll
        for (int n = 0; n < 4; ++n) {
            int col = cq * 64 + n * 16 + fr;
#pragma unroll
            for (int r = 0; r < 4; ++r) {
                int row = rb + r;
                if (row < nRows)
                    HS[(size_t)row * BN + col] = (_Float16)(acc[m][n][r] * s[r]);
            }
        }
    }
}

// ---------------- MFMA f16 GEMM, BM=64 x BN=128 (layer 3) ----------------

__global__ __launch_bounds__(256) void gemm_f16_128(const _Float16* __restrict__ A,
                                                    const _Float16* __restrict__ Bt,
                                                    const float* __restrict__ dinv,
                                                    _Float16* __restrict__ HS,
                                                    int nRows) {
    constexpr int K = 256;
    constexpr int BK = 32;
    constexpr int LDR = 40;
    constexpr int BN = 128;
    constexpr int NF = 2;

    __shared__ __align__(16) _Float16 Al[64 * LDR];
    __shared__ __align__(16) _Float16 Bl[BN * LDR];

    const int tid = threadIdx.x;
    const int wave = tid >> 6;
    const int lane = tid & 63;
    const int row0 = blockIdx.x << 6;

    const int ar = tid >> 2;
    const int ac = (tid & 3) << 3;
    const int arow = min(row0 + ar, nRows - 1);

    const int fr = lane & 15;
    const int k8 = lane >> 4;

    f32x4 acc[4][NF] = {};

    for (int k0 = 0; k0 < K; k0 += BK) {
        half8v av = *(const half8v*)(A + (size_t)arow * K + k0 + ac);
        half8v bv[NF];
#pragma unroll
        for (int j = 0; j < NF; ++j)
            bv[j] = *(const half8v*)(Bt + (size_t)(ar + 64 * j) * K + k0 + ac);
        __syncthreads();
        *(half8v*)(Al + ar * LDR + ac) = av;
#pragma unroll
        for (int j = 0; j < NF; ++j)
            *(half8v*)(Bl + (ar + 64 * j) * LDR + ac) = bv[j];
        __syncthreads();

        half8v af[4], bf[NF];
#pragma unroll
        for (int m = 0; m < 4; ++m)
            af[m] = *(const half8v*)(Al + (m * 16 + fr) * LDR + k8 * 8);
#pragma unroll
        for (int n = 0; n < NF; ++n)
            bf[n] = *(const half8v*)(Bl + (wave * (BN / 4) + n * 16 + fr) * LDR + k8 * 8);
#pragma unroll
        for (int m = 0; m < 4; ++m)
#pragma unroll
            for (int n = 0; n < NF; ++n)
                acc[m][n] = __builtin_amdgcn_mfma_f32_16x16x32_f16(af[m], bf[n], acc[m][n], 0, 0, 0);
    }

#pragma unroll
    for (int m = 0; m < 4; ++m) {
        int rb = row0 + m * 16 + k8 * 4;
        float s[4];
#pragma unroll
        for (int r = 0; r < 4; ++r) s[r] = (rb + r < nRows) ? dinv[rb + r] : 0.f;
#pragma unroll
        for (int n = 0; n < NF; ++n) {
            int col = wave * (BN / 4) + n * 16 + fr;
#pragma unroll
            for (int r = 0; r < 4; ++r) {
                int row = rb + r;
                if (row < nRows)
                    HS[(size_t)row * BN + col] = (_Float16)(acc[m][n][r] * s[r]);
            }
        }
    }
}

// ---------------- aggregation ----------------
// OUT[v] = relu(dinv[v]*(HS[v] + sum_{u->v} HS[u]) + b)
// C=256: 2 nodes/wave, 32 lanes x 16B per row; 4-way unrolled gather;
// nt hints: csr (read-once) and OUT (write-once) bypass L2 retention.

__global__ __launch_bounds__(256) void agg256_f16(const _Float16* __restrict__ HS,
                                                  const int* __restrict__ rowptr,
                                                  const int* __restrict__ csr,
                                                  const float* __restrict__ dinv,
                                                  const float* __restrict__ bias,
                                                  _Float16* __restrict__ OUT, int N) {
    int wid = (blockIdx.x << 2) + (threadIdx.x >> 6);
    int lane = threadIdx.x & 63;
    int v = (wid << 1) + (lane >> 5);
    if (v >= N) return;
    int co = (lane & 31) << 3;  // f16 index; 16B per lane
    const _Float16* base = HS + co;

    f32x8 acc = __builtin_convertvector(*(const half8v*)(base + (size_t)v * 256), f32x8);
    f32x8 acc2 = {};
    int j = rowptr[v], end = rowptr[v + 1];
    for (; j + 4 <= end; j += 4) {
        int u0 = __builtin_nontemporal_load(csr + j);
        int u1 = __builtin_nontemporal_load(csr + j + 1);
        int u2 = __builtin_nontemporal_load(csr + j + 2);
        int u3 = __builtin_nontemporal_load(csr + j + 3);
        half8v a = *(const half8v*)(base + (size_t)u0 * 256);
        half8v b = *(const half8v*)(base + (size_t)u1 * 256);
        half8v c = *(const half8v*)(base + (size_t)u2 * 256);
        half8v d = *(const half8v*)(base + (size_t)u3 * 256);
        acc  += __builtin_convertvector(a, f32x8);
        acc2 += __builtin_convertvector(b, f32x8);
        acc  += __builtin_convertvector(c, f32x8);
        acc2 += __builtin_convertvector(d, f32x8);
    }
    for (; j < end; ++j) {
        int u = __builtin_nontemporal_load(csr + j);
        acc += __builtin_convertvector(*(const half8v*)(base + (size_t)u * 256), f32x8);
    }
    acc += acc2;

    float s = dinv[v];
    f32x4 b0 = *(const f32x4*)(bias + co);
    f32x4 b1 = *(const f32x4*)(bias + co + 4);
    f32x8 bb;
    bb.s0 = b0.x; bb.s1 = b0.y; bb.s2 = b0.z; bb.s3 = b0.w;
    bb.s4 = b1.x; bb.s5 = b1.y; bb.s6 = b1.z; bb.s7 = b1.w;
    f32x8 o = acc * s + bb;
#pragma unroll
    for (int t = 0; t < 8; ++t) o[t] = fmaxf(o[t], 0.f);
    __builtin_nontemporal_store(__builtin_convertvector(o, half8v),
                                (half8v*)(OUT + (size_t)v * 256 + co));
}

// C=128: 4 nodes/wave, 16 lanes x 16B per row; f16 output, no relu.

__global__ __launch_bounds__(256) void agg128_f16(const _Float16* __restrict__ HS,
                                                  const int* __restrict__ rowptr,
                                                  const int* __restrict__ csr,
                                                  const float* __restrict__ dinv,
                                                  const float* __restrict__ bias,
                                                  _Float16* __restrict__ OUT, int N) {
    int wid = (blockIdx.x << 2) + (threadIdx.x >> 6);
    int lane = threadIdx.x & 63;
    int v = (wid << 2) + (lane >> 4);
    if (v >= N) return;
    int co = (lane & 15) << 3;  // f16 index; 16B per lane
    const _Float16* base = HS + co;

    f32x8 acc = __builtin_convertvector(*(const half8v*)(base + (size_t)v * 128), f32x8);
    f32x8 acc2 = {};
    int j = rowptr[v], end = rowptr[v + 1];
    for (; j + 4 <= end; j += 4) {
        int u0 = __builtin_nontemporal_load(csr + j);
        int u1 = __builtin_nontemporal_load(csr + j + 1);
        int u2 = __builtin_nontemporal_load(csr + j + 2);
        int u3 = __builtin_nontemporal_load(csr + j + 3);
        half8v a = *(const half8v*)(base + (size_t)u0 * 128);
        half8v b = *(const half8v*)(base + (size_t)u1 * 128);
        half8v c = *(const half8v*)(base + (size_t)u2 * 128);
        half8v d = *(const half8v*)(base + (size_t)u3 * 128);
        acc  += __builtin_convertvector(a, f32x8);
        acc2 += __builtin_convertvector(b, f32x8);
        acc  += __builtin_convertvector(c, f32x8);
        acc2 += __builtin_convertvector(d, f32x8);
    }
    for (; j < end; ++j) {
        int u = __builtin_nontemporal_load(csr + j);
        acc += __builtin_convertvector(*(const half8v*)(base + (size_t)u * 128), f32x8);
    }
    acc += acc2;

    float s = dinv[v];
    f32x4 b0 = *(const f32x4*)(bias + co);
    f32x4 b1 = *(const f32x4*)(bias + co + 4);
    f32x8 o;
    o.s0 = acc.s0 * s + b0.x; o.s1 = acc.s1 * s + b0.y;
    o.s2 = acc.s2 * s + b0.z; o.s3 = acc.s3 * s + b0.w;
    o.s4 = acc.s4 * s + b1.x; o.s5 = acc.s5 * s + b1.y;
    o.s6 = acc.s6 * s + b1.z; o.s7 = acc.s7 * s + b1.w;
    __builtin_nontemporal_store(__builtin_convertvector(o, half8v),
                                (half8v*)(OUT + (size_t)v * 128 + co));
}

// ---------------- pooling ----------------

__global__ __launch_bounds__(64) void batch_count_kernel(const int* __restrict__ batch, int N,
                                                         int* __restrict__ gcnt) {
    int g = threadIdx.x;
    if (g >= NUM_GRAPHS) return;
    auto lb = [&](int key) {
        int lo = 0, hi = N;
        while (lo < hi) { int mid = (lo + hi) >> 1; if (batch[mid] < key) lo = mid + 1; else hi = mid; }
        return lo;
    };
    gcnt[g] = lb(g + 1) - lb(g);
}

__global__ __launch_bounds__(128) void pool_kernel(const _Float16* __restrict__ H,
                                                   const int* __restrict__ batch,
                                                   float* __restrict__ gsum, int N) {
    const int NODES_PER_BLOCK = 256;
    int c = threadIdx.x;
    int start = blockIdx.x * NODES_PER_BLOCK;
    if (start >= N) return;
    int end = min(start + NODES_PER_BLOCK, N);
    float acc = 0.f;
    int cur = batch[start];
    for (int i = start; i < end; ++i) {
        int b = batch[i];
        if (b != cur) {
            atomicAdd(&gsum[cur * OUT_C + c], acc);
            acc = 0.f;
            cur = b;
        }
        acc += (float)H[(size_t)i * OUT_C + c];
    }
    atomicAdd(&gsum[cur * OUT_C + c], acc);
}

__global__ __launch_bounds__(256) void finalize_kernel(const float* __restrict__ gsum,
                                                       const int* __restrict__ gcnt,
                                                       float* __restrict__ out) {
    int idx = blockIdx.x * 256 + threadIdx.x;
    if (idx < NUM_GRAPHS * OUT_C) {
        int g = idx >> 7;
        out[idx] = gsum[idx] / fmaxf((float)gcnt[g], 1.f);
    }
}

// ---------------- launch ----------------

extern "C" void kernel_launch(void* const* d_in, const int* in_sizes, int n_in,
                              void* d_out, int out_size, void* d_ws, size_t ws_size,
                              hipStream_t stream) {
    const float* x  = (const float*)d_in[0];
    const int* edge = (const int*)d_in[1];
    const int* batch = (const int*)d_in[2];
    const float* W1 = (const float*)d_in[3];
    const float* b1 = (const float*)d_in[4];
    const float* W2 = (const float*)d_in[5];
    const float* b2 = (const float*)d_in[6];
    const float* W3 = (const float*)d_in[7];
    const float* b3 = (const float*)d_in[8];

    const int N = in_sizes[0] / IN_C;
    const int E = in_sizes[1] / 2;
    const int* src = edge;
    const int* dst = edge + E;
    const int M = NBUCK * NBLK;  // histogram size

    char* ws = (char*)d_ws;
    size_t off = 0;
    auto alloc = [&](size_t bytes) -> void* {
        void* p = ws + off;
        off += (bytes + 255) & ~(size_t)255;
        return p;
    };
    _Float16* hA   = (_Float16*)alloc((size_t)N * HID_C * sizeof(_Float16));
    _Float16* hS   = (_Float16*)alloc((size_t)N * HID_C * sizeof(_Float16));
    // union region: CSR-build temporaries (dead after build) alias h3 (live after build)
    size_t ubytes = (size_t)N * OUT_C * sizeof(_Float16);
    char* un      = (char*)alloc(ubytes);
    _Float16* h3  = (_Float16*)un;
    unsigned int* sorted = (unsigned int*)un;                     // 12.8 MB
    int*  ghist   = (int*)(un + (size_t)E * sizeof(unsigned int));// 1 MB
    int*  S       = ghist + M;                                    // 1 MB (+1)
    int*  bsum    = S + M + 1;
    int*  boff    = bsum + 1024;
    _Float16* wt1  = (_Float16*)alloc((size_t)IN_C * HID_C * sizeof(_Float16));
    _Float16* wt2  = (_Float16*)alloc((size_t)HID_C * HID_C * sizeof(_Float16));
    _Float16* wt3  = (_Float16*)alloc((size_t)HID_C * OUT_C * sizeof(_Float16));
    float* dinv    = (float*)alloc((size_t)N * sizeof(float));
    int*   rowptr  = (int*)alloc((size_t)(N + 1) * sizeof(int));
    int*   csr     = (int*)alloc((size_t)E * sizeof(int));
    float* gsum    = (float*)alloc((size_t)NUM_GRAPHS * OUT_C * sizeof(float));
    int*   gcnt    = (int*)alloc((size_t)NUM_GRAPHS * sizeof(int));

    hipMemsetAsync(gsum, 0, (size_t)NUM_GRAPHS * OUT_C * sizeof(float), stream);

    int nb = (N + 255) / 256;
    int mtw = (N + 127) / 128;  // wide gemm blocks (BM=128)
    int mt = (N + 63) / 64;     // layer-3 gemm blocks (BM=64)
    int nbuck_used = (N + 127) >> 7;
    int ab256 = (((N + 1) / 2) + 3) / 4;  // 2 nodes/wave, 4 waves/block
    int ab128 = (((N + 3) / 4) + 3) / 4;  // 4 nodes/wave, 4 waves/block

    // CSR build (atomic-free)
    hist_kernel<<<NBLK, 256, 0, stream>>>(dst, E, ghist);
    scan_bsum_kernel<<<M / 256, 256, 0, stream>>>(ghist, M, bsum);
    scan_boff_kernel<<<1, 1024, 0, stream>>>(bsum, M / 256, boff);
    scan_write_kernel<<<M / 256, 256, 0, stream>>>(ghist, M, boff, S);
    bucket_scatter_kernel<<<NBLK, 256, 0, stream>>>(src, dst, E, S, sorted);
    bucket_csr_kernel<<<nbuck_used, 256, 0, stream>>>(sorted, S, rowptr, csr, N);
    dinv_kernel<<<nb, 256, 0, stream>>>(rowptr, dinv, N);
    batch_count_kernel<<<1, 64, 0, stream>>>(batch, N, gcnt);

    wt_all_kernel<<<(IN_C * HID_C + HID_C * HID_C + HID_C * OUT_C + 255) / 256, 256, 0, stream>>>(
        W1, W2, W3, wt1, wt2, wt3);

    // layer 1 (f32 input, conversion fused into staging)
    gemm_f16_wide<float><<<mtw, 512, 0, stream>>>(x, wt1, dinv, hS, N);
    agg256_f16<<<ab256, 256, 0, stream>>>(hS, rowptr, csr, dinv, b1, hA, N);
    // layer 2
    gemm_f16_wide<_Float16><<<mtw, 512, 0, stream>>>(hA, wt2, dinv, hS, N);
    agg256_f16<<<ab256, 256, 0, stream>>>(hS, rowptr, csr, dinv, b2, hA, N);
    // layer 3 (C=128, f16 out) — h3 reuses the union region (CSR temps now dead)
    gemm_f16_128<<<mt, 256, 0, stream>>>(hA, wt3, dinv, hS, N);
    agg128_f16<<<ab128, 256, 0, stream>>>(hS, rowptr, csr, dinv, b3, h3, N);

    // mean pool
    pool_kernel<<<(N + 255) / 256, 128, 0, stream>>>(h3, batch, gsum, N);
    finalize_kernel<<<(NUM_GRAPHS * OUT_C + 255) / 256, 256, 0, stream>>>(gsum, gcnt, (float*)d_out);
}

// Round 13
// 856.920 us; speedup vs baseline: 1.0845x; 1.0845x over previous
//
#include <hip/hip_runtime.h>

#define IN_C 256
#define HID_C 256
#define OUT_C 128
#define NUM_GRAPHS 64
#define NBLK 256    // blocks for hist/scatter phases
#define NBUCK 1024  // dst buckets (bucket = dst >> 7), N <= 131072

typedef _Float16 half4v __attribute__((ext_vector_type(4)));
typedef _Float16 half8v __attribute__((ext_vector_type(8)));
typedef float f32x4 __attribute__((ext_vector_type(4)));
typedef float f32x8 __attribute__((ext_vector_type(8)));

// ---------------- CSR build: atomic-free (LDS-only atomics) ----------------

__global__ __launch_bounds__(256) void hist_kernel(const int* __restrict__ dst, int E,
                                                   int* __restrict__ ghist) {
    __shared__ int h[NBUCK];
    int tid = threadIdx.x;
#pragma unroll
    for (int j = 0; j < NBUCK / 256; ++j) h[tid + j * 256] = 0;
    __syncthreads();
    int ch = (E + NBLK - 1) / NBLK;
    int base = blockIdx.x * ch;
    int end = min(base + ch, E);
    for (int i = base + tid; i < end; i += 256)
        atomicAdd(&h[dst[i] >> 7], 1);
    __syncthreads();
#pragma unroll
    for (int j = 0; j < NBUCK / 256; ++j) {
        int b = tid + j * 256;
        ghist[b * NBLK + blockIdx.x] = h[b];
    }
}

__global__ __launch_bounds__(256) void scan_bsum_kernel(const int* __restrict__ cnt, int M,
                                                        int* __restrict__ bsum) {
    __shared__ int s[256];
    int tid = threadIdx.x;
    int i = blockIdx.x * 256 + tid;
    int v = (i < M) ? cnt[i] : 0;
    s[tid] = v;
    __syncthreads();
    for (int off = 128; off > 0; off >>= 1) {
        if (tid < off) s[tid] += s[tid + off];
        __syncthreads();
    }
    if (tid == 0) bsum[blockIdx.x] = s[0];
}

__global__ __launch_bounds__(1024) void scan_boff_kernel(const int* __restrict__ bsum, int nb,
                                                         int* __restrict__ boff) {
    __shared__ int s[1024];
    int tid = threadIdx.x;
    int v = (tid < nb) ? bsum[tid] : 0;
    s[tid] = v;
    __syncthreads();
    for (int off = 1; off < 1024; off <<= 1) {
        int t = (tid >= off) ? s[tid - off] : 0;
        __syncthreads();
        s[tid] += t;
        __syncthreads();
    }
    if (tid < nb) boff[tid] = s[tid] - v;  // exclusive
}

__global__ __launch_bounds__(256) void scan_write_kernel(const int* __restrict__ cnt, int M,
                                                         const int* __restrict__ boff,
                                                         int* __restrict__ S) {
    __shared__ int s[256];
    int tid = threadIdx.x;
    int i = blockIdx.x * 256 + tid;
    int v = (i < M) ? cnt[i] : 0;
    s[tid] = v;
    __syncthreads();
    for (int off = 1; off < 256; off <<= 1) {
        int t = (tid >= off) ? s[tid - off] : 0;
        __syncthreads();
        s[tid] += t;
        __syncthreads();
    }
    int incl = s[tid];
    int bo = boff[blockIdx.x];
    if (i < M) S[i] = bo + incl - v;
    if (i == M - 1) S[M] = bo + incl;
}

// Phase 2: scatter edges, packed 4B: (dst&127)<<17 | src   (src < 2^17)

__global__ __launch_bounds__(256) void bucket_scatter_kernel(const int* __restrict__ src,
                                                             const int* __restrict__ dst, int E,
                                                             const int* __restrict__ S,
                                                             unsigned int* __restrict__ sorted) {
    __shared__ int cur[NBUCK];
    int tid = threadIdx.x;
#pragma unroll
    for (int j = 0; j < NBUCK / 256; ++j) {
        int b = tid + j * 256;
        cur[b] = S[b * NBLK + blockIdx.x];
    }
    __syncthreads();
    int ch = (E + NBLK - 1) / NBLK;
    int base = blockIdx.x * ch;
    int end = min(base + ch, E);
    for (int i = base + tid; i < end; i += 256) {
        int d = dst[i], s = src[i];
        int p = atomicAdd(&cur[d >> 7], 1);  // LDS atomic -> global position
        sorted[p] = ((unsigned int)(d & 127) << 17) | (unsigned int)s;
    }
}

// Phase 3: per-bucket (128 nodes) local count/scan/scatter -> rowptr, csr

__global__ __launch_bounds__(256) void bucket_csr_kernel(const unsigned int* __restrict__ sorted,
                                                         const int* __restrict__ S,
                                                         int* __restrict__ rowptr,
                                                         int* __restrict__ csr, int N) {
    __shared__ int cnt[128], sa[128], sb[128], cur[128];
    int b = blockIdx.x;
    int tid = threadIdx.x;
    int lo = S[b << 8];            // b*NBLK
    int hi = S[(b + 1) << 8];
    if (tid < 128) cnt[tid] = 0;
    __syncthreads();
    for (int i = lo + tid; i < hi; i += 256)
        atomicAdd(&cnt[sorted[i] >> 17], 1);
    __syncthreads();
    if (tid < 128) sa[tid] = cnt[tid];
    __syncthreads();
#pragma unroll
    for (int st = 1; st < 128; st <<= 1) {
        if (tid < 128) sb[tid] = sa[tid] + ((tid >= st) ? sa[tid - st] : 0);
        __syncthreads();
        if (tid < 128) sa[tid] = sb[tid];
        __syncthreads();
    }
    if (tid < 128) {
        int offx = sa[tid] - cnt[tid];
        int idx = (b << 7) + tid;
        if (idx <= N) rowptr[idx] = lo + offx;
        cur[tid] = offx;
    }
    __syncthreads();
    for (int i = lo + tid; i < hi; i += 256) {
        unsigned int e = sorted[i];
        int p = atomicAdd(&cur[e >> 17], 1);
        csr[lo + p] = (int)(e & 0x1FFFFu);
    }
}

__global__ __launch_bounds__(256) void dinv_kernel(const int* __restrict__ rowptr,
                                                   float* __restrict__ dinv, int N) {
    int i = blockIdx.x * 256 + threadIdx.x;
    if (i < N) {
        int deg = rowptr[i + 1] - rowptr[i];
        dinv[i] = rsqrtf((float)(deg + 1));  // +1 self loop
    }
}

// ---------------- dtype prep: all three W [K][C] f32 -> Wt [C][K] f16 ----------------

__global__ __launch_bounds__(256) void wt_all_kernel(const float* __restrict__ W1,
                                                     const float* __restrict__ W2,
                                                     const float* __restrict__ W3,
                                                     _Float16* __restrict__ wt1,
                                                     _Float16* __restrict__ wt2,
                                                     _Float16* __restrict__ wt3) {
    int idx = blockIdx.x * 256 + threadIdx.x;
    const int S1 = IN_C * HID_C;           // 65536
    const int S2 = S1 + HID_C * HID_C;     // 131072
    const int S3 = S2 + HID_C * OUT_C;     // 163840
    if (idx < S1) {
        int k = idx >> 8, c = idx & 255;   // C=256
        wt1[c * IN_C + k] = (_Float16)W1[idx];
    } else if (idx < S2) {
        int li = idx - S1;
        int k = li >> 8, c = li & 255;     // C=256
        wt2[c * HID_C + k] = (_Float16)W2[idx - S1];
    } else if (idx < S3) {
        int li = idx - S2;
        int k = li >> 7, c = li & 127;     // C=128
        wt3[c * HID_C + k] = (_Float16)W3[li];
    }
}

// ---------------- MFMA f16 GEMM, BM=128 x BN=256, 512 threads (8 waves) ----------------

template <typename InT>
__global__ __launch_bounds__(512) void gemm_f16_wide(const InT* __restrict__ A,
                                                     const _Float16* __restrict__ Bt,
                                                     const float* __restrict__ dinv,
                                                     _Float16* __restrict__ HS,
                                                     int nRows) {
    constexpr int K = 256;
    constexpr int BK = 32;
    constexpr int LDR = 40;
    constexpr int BN = 256;

    __shared__ __align__(16) _Float16 Al[128 * LDR];
    __shared__ __align__(16) _Float16 Bl[256 * LDR];

    const int tid = threadIdx.x;
    const int wave = tid >> 6;       // 0..7
    const int lane = tid & 63;
    const int row0 = blockIdx.x << 7;  // BM=128

    const int ar = tid >> 2;          // 0..127
    const int ac = (tid & 3) << 3;    // {0,8,16,24}
    const int arow = min(row0 + ar, nRows - 1);

    const int rh = wave >> 2;         // row half 0..1
    const int cq = wave & 3;          // col quad 0..3
    const int fr = lane & 15;
    const int k8 = lane >> 4;

    f32x4 acc[4][4] = {};

    for (int k0 = 0; k0 < K; k0 += BK) {
        half8v av;
        if constexpr (sizeof(InT) == 2) {
            av = *(const half8v*)((const _Float16*)A + (size_t)arow * K + k0 + ac);
        } else {
            const float* ap = (const float*)A + (size_t)arow * K + k0 + ac;
            f32x4 lo = *(const f32x4*)(ap);
            f32x4 hi = *(const f32x4*)(ap + 4);
            half4v l = __builtin_convertvector(lo, half4v);
            half4v h = __builtin_convertvector(hi, half4v);
            av = __builtin_shufflevector(l, h, 0, 1, 2, 3, 4, 5, 6, 7);
        }
        half8v bv0 = *(const half8v*)(Bt + (size_t)ar * K + k0 + ac);
        half8v bv1 = *(const half8v*)(Bt + (size_t)(ar + 128) * K + k0 + ac);
        __syncthreads();
        *(half8v*)(Al + ar * LDR + ac) = av;
        *(half8v*)(Bl + ar * LDR + ac) = bv0;
        *(half8v*)(Bl + (ar + 128) * LDR + ac) = bv1;
        __syncthreads();

        half8v af[4], bf[4];
#pragma unroll
        for (int m = 0; m < 4; ++m)
            af[m] = *(const half8v*)(Al + (rh * 64 + m * 16 + fr) * LDR + k8 * 8);
#pragma unroll
        for (int n = 0; n < 4; ++n)
            bf[n] = *(const half8v*)(Bl + (cq * 64 + n * 16 + fr) * LDR + k8 * 8);
#pragma unroll
        for (int m = 0; m < 4; ++m)
#pragma unroll
            for (int n = 0; n < 4; ++n)
                acc[m][n] = __builtin_amdgcn_mfma_f32_16x16x32_f16(af[m], bf[n], acc[m][n], 0, 0, 0);
    }

#pragma unroll
    for (int m = 0; m < 4; ++m) {
        int rb = row0 + rh * 64 + m * 16 + k8 * 4;
        float s[4];
#pragma unroll
        for (int r = 0; r < 4; ++r) s[r] = (rb + r < nRows) ? dinv[rb + r] : 0.f;
#pragma unroll
        for (int n = 0; n < 4; ++n) {
            int col = cq * 64 + n * 16 + fr;
#pragma unroll
            for (int r = 0; r < 4; ++r) {
                int row = rb + r;
                if (row < nRows)
                    HS[(size_t)row * BN + col] = (_Float16)(acc[m][n][r] * s[r]);
            }
        }
    }
}

// ---------------- MFMA f16 GEMM, BM=64 x BN=128 (layer 3) ----------------

__global__ __launch_bounds__(256) void gemm_f16_128(const _Float16* __restrict__ A,
                                                    const _Float16* __restrict__ Bt,
                                                    const float* __restrict__ dinv,
                                                    _Float16* __restrict__ HS,
                                                    int nRows) {
    constexpr int K = 256;
    constexpr int BK = 32;
    constexpr int LDR = 40;
    constexpr int BN = 128;
    constexpr int NF = 2;

    __shared__ __align__(16) _Float16 Al[64 * LDR];
    __shared__ __align__(16) _Float16 Bl[BN * LDR];

    const int tid = threadIdx.x;
    const int wave = tid >> 6;
    const int lane = tid & 63;
    const int row0 = blockIdx.x << 6;

    const int ar = tid >> 2;
    const int ac = (tid & 3) << 3;
    const int arow = min(row0 + ar, nRows - 1);

    const int fr = lane & 15;
    const int k8 = lane >> 4;

    f32x4 acc[4][NF] = {};

    for (int k0 = 0; k0 < K; k0 += BK) {
        half8v av = *(const half8v*)(A + (size_t)arow * K + k0 + ac);
        half8v bv[NF];
#pragma unroll
        for (int j = 0; j < NF; ++j)
            bv[j] = *(const half8v*)(Bt + (size_t)(ar + 64 * j) * K + k0 + ac);
        __syncthreads();
        *(half8v*)(Al + ar * LDR + ac) = av;
#pragma unroll
        for (int j = 0; j < NF; ++j)
            *(half8v*)(Bl + (ar + 64 * j) * LDR + ac) = bv[j];
        __syncthreads();

        half8v af[4], bf[NF];
#pragma unroll
        for (int m = 0; m < 4; ++m)
            af[m] = *(const half8v*)(Al + (m * 16 + fr) * LDR + k8 * 8);
#pragma unroll
        for (int n = 0; n < NF; ++n)
            bf[n] = *(const half8v*)(Bl + (wave * (BN / 4) + n * 16 + fr) * LDR + k8 * 8);
#pragma unroll
        for (int m = 0; m < 4; ++m)
#pragma unroll
            for (int n = 0; n < NF; ++n)
                acc[m][n] = __builtin_amdgcn_mfma_f32_16x16x32_f16(af[m], bf[n], acc[m][n], 0, 0, 0);
    }

#pragma unroll
    for (int m = 0; m < 4; ++m) {
        int rb = row0 + m * 16 + k8 * 4;
        float s[4];
#pragma unroll
        for (int r = 0; r < 4; ++r) s[r] = (rb + r < nRows) ? dinv[rb + r] : 0.f;
#pragma unroll
        for (int n = 0; n < NF; ++n) {
            int col = wave * (BN / 4) + n * 16 + fr;
#pragma unroll
            for (int r = 0; r < 4; ++r) {
                int row = rb + r;
                if (row < nRows)
                    HS[(size_t)row * BN + col] = (_Float16)(acc[m][n][r] * s[r]);
            }
        }
    }
}

// ---------------- aggregation ----------------
// OUT[v] = relu(dinv[v]*(HS[v] + sum_{u->v} HS[u]) + b)
// C=256: 2 nodes/wave, 32 lanes x 16B per row. Plain loads: csr lines have
// intra-wave reuse (16 idx/line) — nt hints hurt (round 12: +43MB fetch).

__global__ __launch_bounds__(256) void agg256_f16(const _Float16* __restrict__ HS,
                                                  const int* __restrict__ rowptr,
                                                  const int* __restrict__ csr,
                                                  const float* __restrict__ dinv,
                                                  const float* __restrict__ bias,
                                                  _Float16* __restrict__ OUT, int N) {
    int wid = (blockIdx.x << 2) + (threadIdx.x >> 6);
    int lane = threadIdx.x & 63;
    int v = (wid << 1) + (lane >> 5);
    if (v >= N) return;
    int co = (lane & 31) << 3;  // f16 index; 16B per lane
    const _Float16* base = HS + co;

    f32x8 acc = __builtin_convertvector(*(const half8v*)(base + (size_t)v * 256), f32x8);
    f32x8 acc2 = {};
    int j = rowptr[v], end = rowptr[v + 1];
    for (; j + 2 <= end; j += 2) {
        int u0 = csr[j], u1 = csr[j + 1];
        half8v a = *(const half8v*)(base + (size_t)u0 * 256);
        half8v b = *(const half8v*)(base + (size_t)u1 * 256);
        acc  += __builtin_convertvector(a, f32x8);
        acc2 += __builtin_convertvector(b, f32x8);
    }
    if (j < end)
        acc += __builtin_convertvector(*(const half8v*)(base + (size_t)csr[j] * 256), f32x8);
    acc += acc2;

    float s = dinv[v];
    f32x4 b0 = *(const f32x4*)(bias + co);
    f32x4 b1 = *(const f32x4*)(bias + co + 4);
    f32x8 bb;
    bb.s0 = b0.x; bb.s1 = b0.y; bb.s2 = b0.z; bb.s3 = b0.w;
    bb.s4 = b1.x; bb.s5 = b1.y; bb.s6 = b1.z; bb.s7 = b1.w;
    f32x8 o = acc * s + bb;
#pragma unroll
    for (int t = 0; t < 8; ++t) o[t] = fmaxf(o[t], 0.f);
    *(half8v*)(OUT + (size_t)v * 256 + co) = __builtin_convertvector(o, half8v);
}

// C=128: 4 nodes/wave, 16 lanes x 16B per row; f16 output, no relu.

__global__ __launch_bounds__(256) void agg128_f16(const _Float16* __restrict__ HS,
                                                  const int* __restrict__ rowptr,
                                                  const int* __restrict__ csr,
                                                  const float* __restrict__ dinv,
                                                  const float* __restrict__ bias,
                                                  _Float16* __restrict__ OUT, int N) {
    int wid = (blockIdx.x << 2) + (threadIdx.x >> 6);
    int lane = threadIdx.x & 63;
    int v = (wid << 2) + (lane >> 4);
    if (v >= N) return;
    int co = (lane & 15) << 3;  // f16 index; 16B per lane
    const _Float16* base = HS + co;

    f32x8 acc = __builtin_convertvector(*(const half8v*)(base + (size_t)v * 128), f32x8);
    f32x8 acc2 = {};
    int j = rowptr[v], end = rowptr[v + 1];
    for (; j + 2 <= end; j += 2) {
        int u0 = csr[j], u1 = csr[j + 1];
        half8v a = *(const half8v*)(base + (size_t)u0 * 128);
        half8v b = *(const half8v*)(base + (size_t)u1 * 128);
        acc  += __builtin_convertvector(a, f32x8);
        acc2 += __builtin_convertvector(b, f32x8);
    }
    if (j < end)
        acc += __builtin_convertvector(*(const half8v*)(base + (size_t)csr[j] * 128), f32x8);
    acc += acc2;

    float s = dinv[v];
    f32x4 b0 = *(const f32x4*)(bias + co);
    f32x4 b1 = *(const f32x4*)(bias + co + 4);
    f32x8 o;
    o.s0 = acc.s0 * s + b0.x; o.s1 = acc.s1 * s + b0.y;
    o.s2 = acc.s2 * s + b0.z; o.s3 = acc.s3 * s + b0.w;
    o.s4 = acc.s4 * s + b1.x; o.s5 = acc.s5 * s + b1.y;
    o.s6 = acc.s6 * s + b1.z; o.s7 = acc.s7 * s + b1.w;
    *(half8v*)(OUT + (size_t)v * 128 + co) = __builtin_convertvector(o, half8v);
}

// ---------------- pooling ----------------

__global__ __launch_bounds__(64) void batch_count_kernel(const int* __restrict__ batch, int N,
                                                         int* __restrict__ gcnt) {
    int g = threadIdx.x;
    if (g >= NUM_GRAPHS) return;
    auto lb = [&](int key) {
        int lo = 0, hi = N;
        while (lo < hi) { int mid = (lo + hi) >> 1; if (batch[mid] < key) lo = mid + 1; else hi = mid; }
        return lo;
    };
    gcnt[g] = lb(g + 1) - lb(g);
}

__global__ __launch_bounds__(128) void pool_kernel(const _Float16* __restrict__ H,
                                                   const int* __restrict__ batch,
                                                   float* __restrict__ gsum, int N) {
    const int NODES_PER_BLOCK = 256;
    int c = threadIdx.x;
    int start = blockIdx.x * NODES_PER_BLOCK;
    if (start >= N) return;
    int end = min(start + NODES_PER_BLOCK, N);
    float acc = 0.f;
    int cur = batch[start];
    for (int i = start; i < end; ++i) {
        int b = batch[i];
        if (b != cur) {
            atomicAdd(&gsum[cur * OUT_C + c], acc);
            acc = 0.f;
            cur = b;
        }
        acc += (float)H[(size_t)i * OUT_C + c];
    }
    atomicAdd(&gsum[cur * OUT_C + c], acc);
}

__global__ __launch_bounds__(256) void finalize_kernel(const float* __restrict__ gsum,
                                                       const int* __restrict__ gcnt,
                                                       float* __restrict__ out) {
    int idx = blockIdx.x * 256 + threadIdx.x;
    if (idx < NUM_GRAPHS * OUT_C) {
        int g = idx >> 7;
        out[idx] = gsum[idx] / fmaxf((float)gcnt[g], 1.f);
    }
}

// ---------------- launch ----------------

extern "C" void kernel_launch(void* const* d_in, const int* in_sizes, int n_in,
                              void* d_out, int out_size, void* d_ws, size_t ws_size,
                              hipStream_t stream) {
    const float* x  = (const float*)d_in[0];
    const int* edge = (const int*)d_in[1];
    const int* batch = (const int*)d_in[2];
    const float* W1 = (const float*)d_in[3];
    const float* b1 = (const float*)d_in[4];
    const float* W2 = (const float*)d_in[5];
    const float* b2 = (const float*)d_in[6];
    const float* W3 = (const float*)d_in[7];
    const float* b3 = (const float*)d_in[8];

    const int N = in_sizes[0] / IN_C;
    const int E = in_sizes[1] / 2;
    const int* src = edge;
    const int* dst = edge + E;
    const int M = NBUCK * NBLK;  // histogram size

    char* ws = (char*)d_ws;
    size_t off = 0;
    auto alloc = [&](size_t bytes) -> void* {
        void* p = ws + off;
        off += (bytes + 255) & ~(size_t)255;
        return p;
    };
    _Float16* hA   = (_Float16*)alloc((size_t)N * HID_C * sizeof(_Float16));
    _Float16* hS   = (_Float16*)alloc((size_t)N * HID_C * sizeof(_Float16));
    // union region: CSR-build temporaries (dead after build) alias h3 (live after build)
    size_t ubytes = (size_t)N * OUT_C * sizeof(_Float16);
    char* un      = (char*)alloc(ubytes);
    _Float16* h3  = (_Float16*)un;
    unsigned int* sorted = (unsigned int*)un;                     // 12.8 MB
    int*  ghist   = (int*)(un + (size_t)E * sizeof(unsigned int));// 1 MB
    int*  S       = ghist + M;                                    // 1 MB (+1)
    int*  bsum    = S + M + 1;
    int*  boff    = bsum + 1024;
    _Float16* wt1  = (_Float16*)alloc((size_t)IN_C * HID_C * sizeof(_Float16));
    _Float16* wt2  = (_Float16*)alloc((size_t)HID_C * HID_C * sizeof(_Float16));
    _Float16* wt3  = (_Float16*)alloc((size_t)HID_C * OUT_C * sizeof(_Float16));
    float* dinv    = (float*)alloc((size_t)N * sizeof(float));
    int*   rowptr  = (int*)alloc((size_t)(N + 1) * sizeof(int));
    int*   csr     = (int*)alloc((size_t)E * sizeof(int));
    float* gsum    = (float*)alloc((size_t)NUM_GRAPHS * OUT_C * sizeof(float));
    int*   gcnt    = (int*)alloc((size_t)NUM_GRAPHS * sizeof(int));

    hipMemsetAsync(gsum, 0, (size_t)NUM_GRAPHS * OUT_C * sizeof(float), stream);

    int nb = (N + 255) / 256;
    int mtw = (N + 127) / 128;  // wide gemm blocks (BM=128)
    int mt = (N + 63) / 64;     // layer-3 gemm blocks (BM=64)
    int nbuck_used = (N + 127) >> 7;
    int ab256 = (((N + 1) / 2) + 3) / 4;  // 2 nodes/wave, 4 waves/block
    int ab128 = (((N + 3) / 4) + 3) / 4;  // 4 nodes/wave, 4 waves/block

    // CSR build (atomic-free)
    hist_kernel<<<NBLK, 256, 0, stream>>>(dst, E, ghist);
    scan_bsum_kernel<<<M / 256, 256, 0, stream>>>(ghist, M, bsum);
    scan_boff_kernel<<<1, 1024, 0, stream>>>(bsum, M / 256, boff);
    scan_write_kernel<<<M / 256, 256, 0, stream>>>(ghist, M, boff, S);
    bucket_scatter_kernel<<<NBLK, 256, 0, stream>>>(src, dst, E, S, sorted);
    bucket_csr_kernel<<<nbuck_used, 256, 0, stream>>>(sorted, S, rowptr, csr, N);
    dinv_kernel<<<nb, 256, 0, stream>>>(rowptr, dinv, N);
    batch_count_kernel<<<1, 64, 0, stream>>>(batch, N, gcnt);

    wt_all_kernel<<<(IN_C * HID_C + HID_C * HID_C + HID_C * OUT_C + 255) / 256, 256, 0, stream>>>(
        W1, W2, W3, wt1, wt2, wt3);

    // layer 1 (f32 input, conversion fused into staging)
    gemm_f16_wide<float><<<mtw, 512, 0, stream>>>(x, wt1, dinv, hS, N);
    agg256_f16<<<ab256, 256, 0, stream>>>(hS, rowptr, csr, dinv, b1, hA, N);
    // layer 2
    gemm_f16_wide<_Float16><<<mtw, 512, 0, stream>>>(hA, wt2, dinv, hS, N);
    agg256_f16<<<ab256, 256, 0, stream>>>(hS, rowptr, csr, dinv, b2, hA, N);
    // layer 3 (C=128, f16 out) — h3 reuses the union region (CSR temps now dead)
    gemm_f16_128<<<mt, 256, 0, stream>>>(hA, wt3, dinv, hS, N);
    agg128_f16<<<ab128, 256, 0, stream>>>(hS, rowptr, csr, dinv, b3, h3, N);

    // mean pool
    pool_kernel<<<(N + 255) / 256, 128, 0, stream>>>(h3, batch, gsum, N);
    finalize_kernel<<<(NUM_GRAPHS * OUT_C + 255) / 256, 256, 0, stream>>>(gsum, gcnt, (float*)d_out);
}